// Round 1
// baseline (5045.070 us; speedup 1.0000x reference)
//
#include <hip/hip_runtime.h>

// LiquidLayer: h_t = h + DT*(-h/tau + tanh(xW_t + h U^T + b)), T=1024 steps.
// Out = [h_final (32x1024) | states (32x1024x1024)] f32.
// Phase 1: xW GEMM (f32, tiled) written in-place into states region.
// Phase 2: 1024 step kernels (stream-ordered => correct cross-WG sync),
//          h.U^T via bf16 MFMA 16x16x32 (layouts per learn_hip m89/m91).

#define DT 0.1f
#define BB 32
#define TT 1024
#define II 512
#define HH 1024

typedef __attribute__((ext_vector_type(4))) float f32x4;
typedef __attribute__((ext_vector_type(8))) short s16x8;

__device__ __forceinline__ unsigned short f2bf(float f) {
  unsigned int u = __builtin_bit_cast(unsigned int, f);
  u += 0x7fffu + ((u >> 16) & 1u);  // RNE
  return (unsigned short)(u >> 16);
}

// ---------------- U f32 -> bf16 (runs every call; ws is re-poisoned) --------
__global__ __launch_bounds__(256) void cvt_u_kernel(const float* __restrict__ U,
                                                    unsigned short* __restrict__ Ub) {
  int i4 = (blockIdx.x * 256 + threadIdx.x) * 4;
  float4 v = *(const float4*)(U + i4);
  ushort4 o;
  o.x = f2bf(v.x); o.y = f2bf(v.y); o.z = f2bf(v.z); o.w = f2bf(v.w);
  *(ushort4*)(Ub + i4) = o;
}

// ---------------- Phase 1: xW[m][n] = sum_k x[m][k] * W[n][k] (f32) ---------
// M=32768, N=1024, K=512. Block tile 128x128, 256 threads, 8x8 per thread.
#define P1_LDK 36  // LDS row stride (words): pad 32->36; even, 16B-aligned rows

__global__ __launch_bounds__(256) void xw_gemm(const float* __restrict__ x,
                                               const float* __restrict__ W,
                                               float* __restrict__ out) {
  __shared__ __align__(16) float Xs[128 * P1_LDK];
  __shared__ __align__(16) float Ws_s[128 * P1_LDK];
  const int tid = threadIdx.x;
  const int m0 = blockIdx.y * 128;
  const int n0 = blockIdx.x * 128;
  const int ty = tid >> 4;       // 0..15
  const int tx = tid & 15;       // 0..15
  const int lrow = tid >> 3;     // loader: 0..31
  const int lf = tid & 7;        // loader: float4 column 0..7

  float acc[8][8];
#pragma unroll
  for (int i = 0; i < 8; ++i)
#pragma unroll
    for (int j = 0; j < 8; ++j) acc[i][j] = 0.0f;

  for (int kk = 0; kk < II; kk += 32) {
#pragma unroll
    for (int p = 0; p < 4; ++p) {
      int r = lrow + 32 * p;
      float4 vx = *(const float4*)&x[(m0 + r) * II + kk + 4 * lf];
      *(float4*)&Xs[r * P1_LDK + 4 * lf] = vx;
      float4 vw = *(const float4*)&W[(n0 + r) * II + kk + 4 * lf];
      *(float4*)&Ws_s[r * P1_LDK + 4 * lf] = vw;
    }
    __syncthreads();
#pragma unroll
    for (int kq = 0; kq < 32; kq += 4) {
      float4 a[8], b[8];
#pragma unroll
      for (int i = 0; i < 4; ++i) {
        a[i]     = *(const float4*)&Xs[(ty * 4 + i) * P1_LDK + kq];
        a[i + 4] = *(const float4*)&Xs[(ty * 4 + i + 64) * P1_LDK + kq];
      }
#pragma unroll
      for (int j = 0; j < 8; ++j)
        b[j] = *(const float4*)&Ws_s[(tx + 16 * j) * P1_LDK + kq];
#pragma unroll
      for (int i = 0; i < 8; ++i)
#pragma unroll
        for (int j = 0; j < 8; ++j) {
          acc[i][j] += a[i].x * b[j].x;
          acc[i][j] += a[i].y * b[j].y;
          acc[i][j] += a[i].z * b[j].z;
          acc[i][j] += a[i].w * b[j].w;
        }
    }
    __syncthreads();
  }
#pragma unroll
  for (int i = 0; i < 8; ++i) {
    int m = m0 + ty * 4 + (i < 4 ? i : 64 + i - 4);
#pragma unroll
    for (int j = 0; j < 8; ++j)
      out[m * HH + n0 + tx + 16 * j] = acc[i][j];
  }
}

// ---------------- Phase 2: one recurrence step -------------------------------
// Grid 256 = 2 batch-groups(16) x 128 j-groups(8). 64 threads (1 wave).
// LDS rows padded to 1032 bf16 (2064 B = 516 words, 516%32==4 -> <=2-way banks)
#define LDH 1032

__global__ __launch_bounds__(64) void liquid_step(
    const unsigned short* __restrict__ hb,   // h bf16 [32][1024]
    const unsigned short* __restrict__ Ub,   // U bf16 [1024][1024]
    float* __restrict__ hf,                  // h f32  [32][1024] (d_out head)
    unsigned short* __restrict__ hb_out,     // = hb
    float* __restrict__ states,              // [32][1024][1024]; holds xW at t
    const float* __restrict__ bias,
    const float* __restrict__ tau,
    int t) {
  __shared__ __align__(16) unsigned short h_s[16 * LDH];
  __shared__ __align__(16) unsigned short u_s[8 * LDH];

  const int l = threadIdx.x;         // 0..63
  const int bid = blockIdx.x;
  const int mg = bid >> 7;           // 0..1
  const int jg = bid & 127;          // 0..127
  const int n = l & 15;              // MFMA col (j-local, valid if <8)
  const int q = l >> 4;              // 0..3
  const int jloc = n & 7;
  const int j = jg * 8 + jloc;

  // Prefetch epilogue operands early (independent of staging / HBM latency).
  float xw[4], hold[4];
#pragma unroll
  for (int r = 0; r < 4; ++r) {
    int b = mg * 16 + q * 4 + r;               // D row = (lane>>4)*4 + reg
    xw[r] = states[(b * TT + t) * HH + j];     // read-before-overwrite
    hold[r] = hf[b * HH + j];
  }
  float bj = bias[j];
  float invt = 1.0f / tau[j];

  // Stage h (16 rows) + U (8 rows) into LDS; lane l moves 16 B per pass.
#pragma unroll
  for (int r = 0; r < 16; ++r) {
    int b = mg * 16 + r;
#pragma unroll
    for (int hh = 0; hh < 2; ++hh) {
      uint4 v = *(const uint4*)(hb + b * HH + hh * 512 + l * 8);
      *(uint4*)&h_s[r * LDH + hh * 512 + l * 8] = v;
    }
  }
#pragma unroll
  for (int r = 0; r < 8; ++r) {
    int jr = jg * 8 + r;
#pragma unroll
    for (int hh = 0; hh < 2; ++hh) {
      uint4 v = *(const uint4*)(Ub + jr * HH + hh * 512 + l * 8);
      *(uint4*)&u_s[r * LDH + hh * 512 + l * 8] = v;
    }
  }
  __syncthreads();

  // D = A*B: A[m][k] = h[mg*16+m][k], B[k][n] = U[j=n][k].
  // A-frag: lane: A[l&15][q*8 + i]; B-frag: lane: B[q*8 + i][l&15].
  f32x4 acc0 = {0.f, 0.f, 0.f, 0.f}, acc1 = {0.f, 0.f, 0.f, 0.f};
  const int ar = n;       // h_s row
  const int br = jloc;    // u_s row (lanes n>=8 read aliased row; discarded)
  const int ko = q * 8;
#pragma unroll
  for (int kc = 0; kc < 32; kc += 2) {
    s16x8 a0 = *(const s16x8*)&h_s[ar * LDH + kc * 32 + ko];
    s16x8 b0 = *(const s16x8*)&u_s[br * LDH + kc * 32 + ko];
    acc0 = __builtin_amdgcn_mfma_f32_16x16x32_bf16(a0, b0, acc0, 0, 0, 0);
    s16x8 a1 = *(const s16x8*)&h_s[ar * LDH + (kc + 1) * 32 + ko];
    s16x8 b1 = *(const s16x8*)&u_s[br * LDH + (kc + 1) * 32 + ko];
    acc1 = __builtin_amdgcn_mfma_f32_16x16x32_bf16(a1, b1, acc1, 0, 0, 0);
  }
  f32x4 acc = acc0 + acc1;

#pragma unroll
  for (int r = 0; r < 4; ++r) {
    float pre = xw[r] + acc[r] + bj;
    float act = tanhf(pre);
    float hnew = hold[r] + DT * (act - invt * hold[r]);
    if (n < 8) {
      int b = mg * 16 + q * 4 + r;
      hf[b * HH + j] = hnew;
      hb_out[b * HH + j] = f2bf(hnew);
      states[(b * TT + t) * HH + j] = hnew;
    }
  }
}

// ---------------------------------------------------------------------------
extern "C" void kernel_launch(void* const* d_in, const int* in_sizes, int n_in,
                              void* d_out, int out_size, void* d_ws, size_t ws_size,
                              hipStream_t stream) {
  const float* x    = (const float*)d_in[0];
  const float* W    = (const float*)d_in[1];
  const float* U    = (const float*)d_in[2];
  const float* bias = (const float*)d_in[3];
  const float* tau  = (const float*)d_in[4];

  float* out = (float*)d_out;
  float* hf = out;                         // [32][1024] -> h_final
  float* states = out + BB * HH;           // [32][1024][1024]

  unsigned short* Ub = (unsigned short*)d_ws;          // 2 MB
  unsigned short* hb = Ub + (size_t)HH * HH;           // 64 KB

  // init running state (ws/out are poisoned before every call)
  hipMemsetAsync(hf, 0, BB * HH * sizeof(float), stream);
  hipMemsetAsync(hb, 0, BB * HH * sizeof(unsigned short), stream);

  cvt_u_kernel<<<(HH * HH) / (256 * 4), 256, 0, stream>>>(U, Ub);

  // Phase 1: xW into the states region (overwritten in-place by the scan).
  xw_gemm<<<dim3(HH / 128, (BB * TT) / 128), 256, 0, stream>>>(x, W, states);

  // Phase 2: sequential scan; stream order provides cross-WG sync.
  for (int t = 0; t < TT; ++t) {
    liquid_step<<<256, 64, 0, stream>>>(hb, Ub, hf, hb, states, bias, tau, t);
  }
}